// Round 7
// baseline (90.908 us; speedup 1.0000x reference)
//
#include <hip/hip_runtime.h>
#include <hip/hip_bf16.h>
#include <math.h>

#define B_PAIRS 2048
#define N_ROWS  4096
#define D_DIM   256
#define INV_T   2.0f

typedef __attribute__((ext_vector_type(4))) float  floatx4;

// ---- workspace layout ----
// [0, 1MB)        : zn8 (fp8 e4m3, 4096 x 256, row-major bytes)
// [1MB, +16KB)    : S[4096]  (fp32, sum_{j!=i} exp(sim_ij))
// then            : posSum (fp32)

// ---------- kernel 1: row-normalize fp32 -> fp8 e4m3 (1 wave per row) -------
// Also zero-inits S[row] and posSum.
__global__ __launch_bounds__(256)
void ntx_normalize(const float* __restrict__ z_i,
                   const float* __restrict__ z_j,
                   unsigned* __restrict__ zn8,   // 4096 x 64 packed fp8x4
                   float* __restrict__ S,
                   float* __restrict__ posSum) {
    const int w    = threadIdx.x >> 6;               // wave 0..3
    const int lane = threadIdx.x & 63;
    const int row  = blockIdx.x * 4 + w;             // 0..4095
    const float* src = (row < B_PAIRS) ? (z_i + (size_t)row * D_DIM)
                                       : (z_j + (size_t)(row - B_PAIRS) * D_DIM);
    const float4 v = *(const float4*)(src + lane * 4);
    float ss = v.x * v.x + v.y * v.y + v.z * v.z + v.w * v.w;
    #pragma unroll
    for (int off = 32; off > 0; off >>= 1) ss += __shfl_xor(ss, off, 64);
    const float rn = 1.0f / fmaxf(sqrtf(ss), 1e-8f);
    unsigned pk = 0;
    pk = __builtin_amdgcn_cvt_pk_fp8_f32(v.x * rn, v.y * rn, pk, false);
    pk = __builtin_amdgcn_cvt_pk_fp8_f32(v.z * rn, v.w * rn, pk, true);
    zn8[(size_t)row * (D_DIM / 4) + lane] = pk;
    if (lane == 0) S[row] = 0.0f;
    if (blockIdx.x == 0 && threadIdx.x == 0) *posSum = 0.0f;
}

// ---------- kernel 2: upper-triangle sim tiles, DIRECT-GLOBAL fragments -----
// No LDS staging, no K-loop barriers: each lane gathers its 8-B fp8 fragments
// straight from L2 (zn8 is 1 MB -> L2-resident). 8 K-steps x 16 MFMA fully
// unrolled so the compiler interleaves loads ahead of MFMAs (fine vmcnt).
#define BM 128
#define BN 128
#define N_TILES 528            // 32 diag + 496 strictly-upper (32x32 tile grid)

__global__ __launch_bounds__(256)
void ntx_simtile(const unsigned char* __restrict__ zn8,
                 float* __restrict__ S,
                 float* __restrict__ posSum) {
    // linear block id -> upper-triangle (by, bx), bx >= by
    int t = blockIdx.x, by = 0, rowlen = 32;
    while (t >= rowlen) { t -= rowlen; by++; rowlen--; }
    const int bx = by + t;

    const int tid  = threadIdx.x;
    const int lane = tid & 63;
    const int w    = tid >> 6;           // wave 0..3
    const int wr   = w >> 1;             // wave row strip (0..1)
    const int wc   = w & 1;              // wave col strip (0..1)
    const int quad = lane >> 4;          // 0..3
    const int l16  = lane & 15;

    const int rowA0 = by * BM;
    const int rowB0 = bx * BN;
    const bool isDiag = (rowA0 == rowB0);
    const bool isPos  = (rowB0 == (rowA0 ^ B_PAIRS));

    // Per-lane fragment base pointers: A[m=l16][k=quad*8+j], row = 256 B.
    const unsigned char* aP[4];
    const unsigned char* bP[4];
    #pragma unroll
    for (int f = 0; f < 4; f++) {
        aP[f] = zn8 + (size_t)(rowA0 + wr * 64 + f * 16 + l16) * D_DIM + quad * 8;
        bP[f] = zn8 + (size_t)(rowB0 + wc * 64 + f * 16 + l16) * D_DIM + quad * 8;
    }

    floatx4 acc[4][4];
    #pragma unroll
    for (int i = 0; i < 4; i++)
        #pragma unroll
        for (int j = 0; j < 4; j++)
            acc[i][j] = (floatx4){0.f, 0.f, 0.f, 0.f};

    #pragma unroll
    for (int step = 0; step < D_DIM / 32; step++) {   // 8 K-steps of K=32
        long afr[4], bfr[4];
        #pragma unroll
        for (int f = 0; f < 4; f++) {
            afr[f] = *(const long*)(const void*)(aP[f] + step * 32);
            bfr[f] = *(const long*)(const void*)(bP[f] + step * 32);
        }
        #pragma unroll
        for (int fi = 0; fi < 4; fi++)
            #pragma unroll
            for (int fj = 0; fj < 4; fj++)
                acc[fi][fj] = __builtin_amdgcn_mfma_f32_16x16x32_fp8_fp8(
                    afr[fi], bfr[fj], acc[fi][fj], 0, 0, 0);
    }

    // Epilogue. C/D layout (16x16, dtype-independent): col = l16, row = quad*4+reg.
    // Row sums -> S[rowA0+ri]; off-diag tiles also col-sum -> S[rowB0+rj]
    // (symmetry). Positive pairs contribute 2*v to scalar posSum.
    float cs[4] = {0.f, 0.f, 0.f, 0.f};
    float psum = 0.f;
    #pragma unroll
    for (int fi = 0; fi < 4; fi++) {
        float rs[4] = {0.f, 0.f, 0.f, 0.f};
        #pragma unroll
        for (int fj = 0; fj < 4; fj++) {
            const int rj = wc * 64 + fj * 16 + l16;
            #pragma unroll
            for (int reg = 0; reg < 4; reg++) {
                const int ri = wr * 64 + fi * 16 + quad * 4 + reg;
                const float v = acc[fi][fj][reg] * INV_T;
                const bool d = (ri == rj);
                if (isPos && d) psum += 2.0f * v;
                const float e = (isDiag && d) ? 0.f : __expf(v);
                rs[reg] += e;
                cs[fj]  += e;
            }
        }
        #pragma unroll
        for (int reg = 0; reg < 4; reg++) {
            float r = rs[reg];
            r += __shfl_xor(r, 1, 16);
            r += __shfl_xor(r, 2, 16);
            r += __shfl_xor(r, 4, 16);
            r += __shfl_xor(r, 8, 16);
            if (l16 == 0)
                atomicAdd(&S[rowA0 + wr * 64 + fi * 16 + quad * 4 + reg], r);
        }
    }
    if (!isDiag) {
        #pragma unroll
        for (int fj = 0; fj < 4; fj++) {
            float c = cs[fj];
            c += __shfl_xor(c, 16, 64);
            c += __shfl_xor(c, 32, 64);
            if (quad == 0)
                atomicAdd(&S[rowB0 + wc * 64 + fj * 16 + l16], c);
        }
    }
    if (isPos) {
        psum += __shfl_xor(psum, 1, 64);  psum += __shfl_xor(psum, 2, 64);
        psum += __shfl_xor(psum, 4, 64);  psum += __shfl_xor(psum, 8, 64);
        psum += __shfl_xor(psum, 16, 64); psum += __shfl_xor(psum, 32, 64);
        __shared__ float pred[4];
        if (lane == 0) pred[w] = psum;
        __syncthreads();
        if (tid == 0)
            atomicAdd(posSum, pred[0] + pred[1] + pred[2] + pred[3]);
    }
}

// ---------- kernel 3: loss = (sum log S_i - posSum) / N ----------
__global__ __launch_bounds__(1024)
void ntx_finalize(const float* __restrict__ S,
                  const float* __restrict__ posSum,
                  float* __restrict__ out) {
    const int tid = threadIdx.x;   // 1024 threads
    float acc = 0.f;
    #pragma unroll
    for (int c = 0; c < 4; c++)
        acc += __logf(S[tid + c * 1024]);
    #pragma unroll
    for (int off = 32; off > 0; off >>= 1) acc += __shfl_xor(acc, off, 64);
    __shared__ float red[16];
    if ((tid & 63) == 0) red[tid >> 6] = acc;
    __syncthreads();
    if (tid == 0) {
        float s = 0.f;
        #pragma unroll
        for (int k = 0; k < 16; k++) s += red[k];
        out[0] = (s - *posSum) / (float)N_ROWS;
    }
}

extern "C" void kernel_launch(void* const* d_in, const int* in_sizes, int n_in,
                              void* d_out, int out_size, void* d_ws, size_t ws_size,
                              hipStream_t stream) {
    const float* z_i = (const float*)d_in[0];
    const float* z_j = (const float*)d_in[1];
    float* out = (float*)d_out;

    unsigned char* zn8 = (unsigned char*)d_ws;
    float* S      = (float*)((char*)d_ws + (size_t)N_ROWS * D_DIM);  // 1 MB
    float* posSum = S + N_ROWS;

    ntx_normalize<<<N_ROWS / 4, 256, 0, stream>>>(z_i, z_j, (unsigned*)zn8, S, posSum);
    ntx_simtile<<<N_TILES, 256, 0, stream>>>(zn8, S, posSum);
    ntx_finalize<<<1, 1024, 0, stream>>>(S, posSum, out);
}

// Round 9
// 84.636 us; speedup vs baseline: 1.0741x; 1.0741x over previous
//
#include <hip/hip_runtime.h>
#include <hip/hip_bf16.h>
#include <math.h>

#define B_PAIRS 2048
#define N_ROWS  4096
#define D_DIM   256
#define INV_T   2.0f

typedef __attribute__((ext_vector_type(4))) float  floatx4;

// ---- workspace layout ----
// [0, 1MB)        : zn8 (fp8 e4m3, 4096 x 256, row-major bytes)
// [1MB, +16KB)    : S[4096]  (fp32, sum_{j!=i} exp(sim_ij))
// then            : posSum (fp32)

__device__ __forceinline__ void async_copy16(const void* gsrc, void* ldst) {
    __builtin_amdgcn_global_load_lds(
        (__attribute__((address_space(1))) void*)gsrc,
        (__attribute__((address_space(3))) void*)ldst,
        16, 0, 0);
}

// ---------- kernel 1: row-normalize fp32 -> fp8 e4m3 (1 wave per row) -------
// Also zero-inits S[row] and posSum.
__global__ __launch_bounds__(256)
void ntx_normalize(const float* __restrict__ z_i,
                   const float* __restrict__ z_j,
                   unsigned* __restrict__ zn8,   // 4096 x 64 packed fp8x4
                   float* __restrict__ S,
                   float* __restrict__ posSum) {
    const int w    = threadIdx.x >> 6;               // wave 0..3
    const int lane = threadIdx.x & 63;
    const int row  = blockIdx.x * 4 + w;             // 0..4095
    const float* src = (row < B_PAIRS) ? (z_i + (size_t)row * D_DIM)
                                       : (z_j + (size_t)(row - B_PAIRS) * D_DIM);
    const float4 v = *(const float4*)(src + lane * 4);
    float ss = v.x * v.x + v.y * v.y + v.z * v.z + v.w * v.w;
    #pragma unroll
    for (int off = 32; off > 0; off >>= 1) ss += __shfl_xor(ss, off, 64);
    const float rn = 1.0f / fmaxf(sqrtf(ss), 1e-8f);
    unsigned pk = 0;
    pk = __builtin_amdgcn_cvt_pk_fp8_f32(v.x * rn, v.y * rn, pk, false);
    pk = __builtin_amdgcn_cvt_pk_fp8_f32(v.z * rn, v.w * rn, pk, true);
    zn8[(size_t)row * (D_DIM / 4) + lane] = pk;
    if (lane == 0) S[row] = 0.0f;
    if (blockIdx.x == 0 && threadIdx.x == 0) *posSum = 0.0f;
}

// ---------- kernel 2: upper-triangle 64x64 sim tiles (fp8 MFMA) -------------
// 64x64 tiles -> 2080 blocks (~8/CU co-resident) so per-block barrier/latency
// stalls overlap across blocks (round-6 diagnosis: 128-tiles = 2 blocks/CU,
// ~90% stall, byte-halving neutral => latency-bound not bandwidth-bound).
#define BM 64
#define BN 64
#define BK 32                  // 32 fp8 = 32 B per row per K-iter
#define GT 64                  // 4096/64 tile grid side
#define N_TILES (GT * (GT + 1) / 2)     // 2080

__global__ __launch_bounds__(256)
void ntx_simtile(const unsigned char* __restrict__ zn8,
                 float* __restrict__ S,
                 float* __restrict__ posSum) {
    __shared__ __align__(16) unsigned char As[BM * BK];   // 2 KB
    __shared__ __align__(16) unsigned char Bs[BN * BK];   // 2 KB

    // linear block id -> upper-triangle (by, bx), bx >= by
    int t = blockIdx.x, by = 0, rowlen = GT;
    while (t >= rowlen) { t -= rowlen; by++; rowlen--; }
    const int bx = by + t;

    const int tid  = threadIdx.x;
    const int lane = tid & 63;
    const int w    = tid >> 6;           // wave 0..3
    const int wr   = w >> 1;             // wave row strip (0..1) -> 32 rows
    const int wc   = w & 1;              // wave col strip (0..1) -> 32 cols
    const int quad = lane >> 4;          // 0..3
    const int l16  = lane & 15;

    const int rowA0 = by * BM;
    const int rowB0 = bx * BN;
    const bool isDiag = (by == bx);
    const bool isPos  = (rowB0 == (rowA0 ^ B_PAIRS));

    floatx4 acc[2][2];
    #pragma unroll
    for (int i = 0; i < 2; i++)
        #pragma unroll
        for (int j = 0; j < 2; j++)
            acc[i][j] = (floatx4){0.f, 0.f, 0.f, 0.f};

    // Staging role: waves 0-1 stage A (chunks 0..127), waves 2-3 stage B.
    // One 16-B chunk per thread per iter; dest = wave-uniform base + lane*16.
    const bool stageA = (w < 2);
    const int  chunk  = (stageA ? w : (w - 2)) * 64 + lane;   // 0..127
    const int  srow   = chunk >> 1;          // tile row 0..63
    const int  skc    = chunk & 1;           // 16-B half of the 32-B row
    const unsigned char* sbase = zn8 +
        (size_t)((stageA ? rowA0 : rowB0) + srow) * D_DIM + skc * 16;
    unsigned char* ldst = (stageA ? As : Bs) + chunk * 16;

    for (int k0 = 0; k0 < D_DIM; k0 += BK) {
        async_copy16(sbase + k0, ldst);
        __syncthreads();

        // Fragments: 8 fp8 = 8 B per lane; A[m=l16][k=quad*8+j], row = 32 B.
        long afr[2], bfr[2];
        #pragma unroll
        for (int fi = 0; fi < 2; fi++) {
            const int ar = wr * 32 + fi * 16 + l16;
            afr[fi] = *(const long*)(const void*)(As + ar * BK + quad * 8);
        }
        #pragma unroll
        for (int fj = 0; fj < 2; fj++) {
            const int br = wc * 32 + fj * 16 + l16;
            bfr[fj] = *(const long*)(const void*)(Bs + br * BK + quad * 8);
        }
        #pragma unroll
        for (int fi = 0; fi < 2; fi++)
            #pragma unroll
            for (int fj = 0; fj < 2; fj++)
                acc[fi][fj] = __builtin_amdgcn_mfma_f32_16x16x32_fp8_fp8(
                    afr[fi], bfr[fj], acc[fi][fj], 0, 0, 0);
        __syncthreads();
    }

    // Epilogue. C/D layout (16x16, dtype-independent): col=l16, row=quad*4+reg.
    // Row sums -> S[rowA0+ri]; off-diag also col-sums -> S[rowB0+rj] (symmetry).
    float cs[2] = {0.f, 0.f};
    float psum = 0.f;
    #pragma unroll
    for (int fi = 0; fi < 2; fi++) {
        float rs[4] = {0.f, 0.f, 0.f, 0.f};
        #pragma unroll
        for (int fj = 0; fj < 2; fj++) {
            const int rj = wc * 32 + fj * 16 + l16;
            #pragma unroll
            for (int reg = 0; reg < 4; reg++) {
                const int ri = wr * 32 + fi * 16 + quad * 4 + reg;
                const float v = acc[fi][fj][reg] * INV_T;
                const bool d = (ri == rj);
                if (isPos && d) psum += 2.0f * v;
                const float e = (isDiag && d) ? 0.f : __expf(v);
                rs[reg] += e;
                cs[fj]  += e;
            }
        }
        #pragma unroll
        for (int reg = 0; reg < 4; reg++) {
            float r = rs[reg];
            r += __shfl_xor(r, 1, 16);
            r += __shfl_xor(r, 2, 16);
            r += __shfl_xor(r, 4, 16);
            r += __shfl_xor(r, 8, 16);
            if (l16 == 0)
                atomicAdd(&S[rowA0 + wr * 32 + fi * 16 + quad * 4 + reg], r);
        }
    }
    if (!isDiag) {
        #pragma unroll
        for (int fj = 0; fj < 2; fj++) {
            float c = cs[fj];
            c += __shfl_xor(c, 16, 64);
            c += __shfl_xor(c, 32, 64);
            if (quad == 0)
                atomicAdd(&S[rowB0 + wc * 32 + fj * 16 + l16], c);
        }
    }
    if (isPos) {
        psum += __shfl_xor(psum, 1, 64);  psum += __shfl_xor(psum, 2, 64);
        psum += __shfl_xor(psum, 4, 64);  psum += __shfl_xor(psum, 8, 64);
        psum += __shfl_xor(psum, 16, 64); psum += __shfl_xor(psum, 32, 64);
        __shared__ float pred[4];
        if (lane == 0) pred[w] = psum;
        __syncthreads();
        if (tid == 0)
            atomicAdd(posSum, pred[0] + pred[1] + pred[2] + pred[3]);
    }
}

// ---------- kernel 3: loss = (sum log S_i - posSum) / N ----------
__global__ __launch_bounds__(1024)
void ntx_finalize(const float* __restrict__ S,
                  const float* __restrict__ posSum,
                  float* __restrict__ out) {
    const int tid = threadIdx.x;   // 1024 threads
    float acc = 0.f;
    #pragma unroll
    for (int c = 0; c < 4; c++)
        acc += __logf(S[tid + c * 1024]);
    #pragma unroll
    for (int off = 32; off > 0; off >>= 1) acc += __shfl_xor(acc, off, 64);
    __shared__ float red[16];
    if ((tid & 63) == 0) red[tid >> 6] = acc;
    __syncthreads();
    if (tid == 0) {
        float s = 0.f;
        #pragma unroll
        for (int k = 0; k < 16; k++) s += red[k];
        out[0] = (s - *posSum) / (float)N_ROWS;
    }
}

extern "C" void kernel_launch(void* const* d_in, const int* in_sizes, int n_in,
                              void* d_out, int out_size, void* d_ws, size_t ws_size,
                              hipStream_t stream) {
    const float* z_i = (const float*)d_in[0];
    const float* z_j = (const float*)d_in[1];
    float* out = (float*)d_out;

    unsigned char* zn8 = (unsigned char*)d_ws;
    float* S      = (float*)((char*)d_ws + (size_t)N_ROWS * D_DIM);  // 1 MB
    float* posSum = S + N_ROWS;

    ntx_normalize<<<N_ROWS / 4, 256, 0, stream>>>(z_i, z_j, (unsigned*)zn8, S, posSum);
    ntx_simtile<<<N_TILES, 256, 0, stream>>>(zn8, S, posSum);
    ntx_finalize<<<1, 1024, 0, stream>>>(S, posSum, out);
}

// Round 10
// 76.359 us; speedup vs baseline: 1.1905x; 1.1084x over previous
//
#include <hip/hip_runtime.h>
#include <hip/hip_bf16.h>
#include <math.h>

#define B_PAIRS 2048
#define N_ROWS  4096
#define D_DIM   256
#define INV_T   2.0f

typedef __attribute__((ext_vector_type(4))) float  floatx4;

// ---- workspace layout ----
// [0, 1MB)   : zn8t — fp8 e4m3, K-BLOCKED: segment s holds k=[32s,32s+32) for
//              all rows: byte addr = s*131072 + row*32 + (k&31). Each segment
//              is row-contiguous -> simtile stages it with LINEAR copies.
// [1MB,+16KB): S[4096] (fp32, sum_{j!=i} exp(sim_ij))
// then       : posSum (fp32)

__device__ __forceinline__ void async_copy16(const void* gsrc, void* ldst) {
    __builtin_amdgcn_global_load_lds(
        (__attribute__((address_space(1))) void*)gsrc,
        (__attribute__((address_space(3))) void*)ldst,
        16, 0, 0);
}

// ---------- kernel 1: row-normalize fp32 -> fp8 e4m3, K-blocked store -------
// Also zero-inits S[row] and posSum.
__global__ __launch_bounds__(256)
void ntx_normalize(const float* __restrict__ z_i,
                   const float* __restrict__ z_j,
                   unsigned* __restrict__ zn8t,  // dword view of K-blocked buf
                   float* __restrict__ S,
                   float* __restrict__ posSum) {
    const int w    = threadIdx.x >> 6;               // wave 0..3
    const int lane = threadIdx.x & 63;
    const int row  = blockIdx.x * 4 + w;             // 0..4095
    const float* src = (row < B_PAIRS) ? (z_i + (size_t)row * D_DIM)
                                       : (z_j + (size_t)(row - B_PAIRS) * D_DIM);
    const float4 v = *(const float4*)(src + lane * 4);   // k = lane*4 .. +3
    float ss = v.x * v.x + v.y * v.y + v.z * v.z + v.w * v.w;
    #pragma unroll
    for (int off = 32; off > 0; off >>= 1) ss += __shfl_xor(ss, off, 64);
    const float rn = 1.0f / fmaxf(sqrtf(ss), 1e-8f);
    unsigned pk = 0;
    pk = __builtin_amdgcn_cvt_pk_fp8_f32(v.x * rn, v.y * rn, pk, false);
    pk = __builtin_amdgcn_cvt_pk_fp8_f32(v.z * rn, v.w * rn, pk, true);
    // k = lane*4 -> segment s = lane>>3, dword-in-seg = row*8 + (lane&7)
    zn8t[(size_t)(lane >> 3) * 32768 + row * 8 + (lane & 7)] = pk;
    if (lane == 0) S[row] = 0.0f;
    if (blockIdx.x == 0 && threadIdx.x == 0) *posSum = 0.0f;
}

// ---------- kernel 2: upper-triangle sim tiles, SINGLE-DRAIN K loop ---------
// Full K (256) staged at once: 64 KB LDS, ONE vmcnt-drain + barrier per block
// (rounds 6/9 evidence: per-block time ~ 8 serial staging drains, not bytes).
#define BM 128
#define BN 128
#define N_TILES 528            // 32 diag + 496 strictly-upper (32x32 tile grid)

__global__ __launch_bounds__(256)
void ntx_simtile(const unsigned char* __restrict__ zn8t,
                 float* __restrict__ S,
                 float* __restrict__ posSum) {
    __shared__ __align__(16) unsigned char As[8 * 128 * 32];   // 32 KB
    __shared__ __align__(16) unsigned char Bs[8 * 128 * 32];   // 32 KB

    // linear block id -> upper-triangle (by, bx), bx >= by
    int t = blockIdx.x, by = 0, rowlen = 32;
    while (t >= rowlen) { t -= rowlen; by++; rowlen--; }
    const int bx = by + t;

    const int tid  = threadIdx.x;
    const int lane = tid & 63;
    const int w    = tid >> 6;           // wave 0..3
    const int wr   = w >> 1;             // wave row strip (0..1)
    const int wc   = w & 1;              // wave col strip (0..1)
    const int quad = lane >> 4;          // 0..3
    const int l16  = lane & 15;

    const int rowA0 = by * BM;
    const int rowB0 = bx * BN;
    const bool isDiag = (by == bx);
    const bool isPos  = (rowB0 == (rowA0 ^ B_PAIRS));

    // Stage ALL 8 K-segments for A and B: 16 linear 16-B copies per thread.
    // Segment s of tile rows [r0, r0+128) is contiguous 4 KB at
    // zn8t + s*131072 + r0*32. LDS dest stays base + tid*16 (linear). 
    #pragma unroll
    for (int s = 0; s < 8; s++) {
        async_copy16(zn8t + (size_t)s * 131072 + rowA0 * 32 + tid * 16,
                     As + s * 4096 + tid * 16);
        async_copy16(zn8t + (size_t)s * 131072 + rowB0 * 32 + tid * 16,
                     Bs + s * 4096 + tid * 16);
    }
    __syncthreads();   // the ONLY staging drain

    floatx4 acc[4][4];
    #pragma unroll
    for (int i = 0; i < 4; i++)
        #pragma unroll
        for (int j = 0; j < 4; j++)
            acc[i][j] = (floatx4){0.f, 0.f, 0.f, 0.f};

    #pragma unroll
    for (int s = 0; s < 8; s++) {        // K-steps, no barriers
        // frag k = s*32 + quad*8 + j; LDS row stride 32 B (4-way mild conflict)
        long afr[4], bfr[4];
        #pragma unroll
        for (int fi = 0; fi < 4; fi++) {
            const int ar = wr * 64 + fi * 16 + l16;
            afr[fi] = *(const long*)(const void*)(As + s * 4096 + ar * 32 + quad * 8);
        }
        #pragma unroll
        for (int fj = 0; fj < 4; fj++) {
            const int br = wc * 64 + fj * 16 + l16;
            bfr[fj] = *(const long*)(const void*)(Bs + s * 4096 + br * 32 + quad * 8);
        }
        #pragma unroll
        for (int fi = 0; fi < 4; fi++)
            #pragma unroll
            for (int fj = 0; fj < 4; fj++)
                acc[fi][fj] = __builtin_amdgcn_mfma_f32_16x16x32_fp8_fp8(
                    afr[fi], bfr[fj], acc[fi][fj], 0, 0, 0);
    }

    // Epilogue (round-6 verbatim). C/D layout: col=l16, row=quad*4+reg.
    float cs[4] = {0.f, 0.f, 0.f, 0.f};
    float psum = 0.f;
    #pragma unroll
    for (int fi = 0; fi < 4; fi++) {
        float rs[4] = {0.f, 0.f, 0.f, 0.f};
        #pragma unroll
        for (int fj = 0; fj < 4; fj++) {
            const int rj = wc * 64 + fj * 16 + l16;
            #pragma unroll
            for (int reg = 0; reg < 4; reg++) {
                const int ri = wr * 64 + fi * 16 + quad * 4 + reg;
                const float v = acc[fi][fj][reg] * INV_T;
                const bool d = (ri == rj);
                if (isPos && d) psum += 2.0f * v;
                const float e = (isDiag && d) ? 0.f : __expf(v);
                rs[reg] += e;
                cs[fj]  += e;
            }
        }
        #pragma unroll
        for (int reg = 0; reg < 4; reg++) {
            float r = rs[reg];
            r += __shfl_xor(r, 1, 16);
            r += __shfl_xor(r, 2, 16);
            r += __shfl_xor(r, 4, 16);
            r += __shfl_xor(r, 8, 16);
            if (l16 == 0)
                atomicAdd(&S[rowA0 + wr * 64 + fi * 16 + quad * 4 + reg], r);
        }
    }
    if (!isDiag) {
        #pragma unroll
        for (int fj = 0; fj < 4; fj++) {
            float c = cs[fj];
            c += __shfl_xor(c, 16, 64);
            c += __shfl_xor(c, 32, 64);
            if (quad == 0)
                atomicAdd(&S[rowB0 + wc * 64 + fj * 16 + l16], c);
        }
    }
    if (isPos) {
        psum += __shfl_xor(psum, 1, 64);  psum += __shfl_xor(psum, 2, 64);
        psum += __shfl_xor(psum, 4, 64);  psum += __shfl_xor(psum, 8, 64);
        psum += __shfl_xor(psum, 16, 64); psum += __shfl_xor(psum, 32, 64);
        __shared__ float pred[4];
        if (lane == 0) pred[w] = psum;
        __syncthreads();
        if (tid == 0)
            atomicAdd(posSum, pred[0] + pred[1] + pred[2] + pred[3]);
    }
}

// ---------- kernel 3: loss = (sum log S_i - posSum) / N ----------
__global__ __launch_bounds__(1024)
void ntx_finalize(const float* __restrict__ S,
                  const float* __restrict__ posSum,
                  float* __restrict__ out) {
    const int tid = threadIdx.x;   // 1024 threads
    float acc = 0.f;
    #pragma unroll
    for (int c = 0; c < 4; c++)
        acc += __logf(S[tid + c * 1024]);
    #pragma unroll
    for (int off = 32; off > 0; off >>= 1) acc += __shfl_xor(acc, off, 64);
    __shared__ float red[16];
    if ((tid & 63) == 0) red[tid >> 6] = acc;
    __syncthreads();
    if (tid == 0) {
        float s = 0.f;
        #pragma unroll
        for (int k = 0; k < 16; k++) s += red[k];
        out[0] = (s - *posSum) / (float)N_ROWS;
    }
}

extern "C" void kernel_launch(void* const* d_in, const int* in_sizes, int n_in,
                              void* d_out, int out_size, void* d_ws, size_t ws_size,
                              hipStream_t stream) {
    const float* z_i = (const float*)d_in[0];
    const float* z_j = (const float*)d_in[1];
    float* out = (float*)d_out;

    unsigned char* zn8t = (unsigned char*)d_ws;
    float* S      = (float*)((char*)d_ws + (size_t)N_ROWS * D_DIM);  // 1 MB
    float* posSum = S + N_ROWS;

    ntx_normalize<<<N_ROWS / 4, 256, 0, stream>>>(z_i, z_j, (unsigned*)zn8t, S, posSum);
    ntx_simtile<<<N_TILES, 256, 0, stream>>>(zn8t, S, posSum);
    ntx_finalize<<<1, 1024, 0, stream>>>(S, posSum, out);
}